// Round 1
// 622.518 us; speedup vs baseline: 1.4227x; 1.4227x over previous
//
#include <hip/hip_runtime.h>

#define HEADS 16
#define SEQL 32
#define HD 64
#define PASTN 32768
#define TOTN 32800
#define NE 1024
#define CHUNK 512      // keys per past chunk
#define NPC 64         // number of past chunks
#define NCHUNK 65      // 64 past chunks + 1 new-key chunk
#define KT 32          // keys per LDS tile
#define SLDP 36        // Ss leading dim (multiple of 4, breaks softmax conflicts)
#define NEGV -10000.0f

// ---------------- kernel 1: qkv = x @ w_attn + b_attn ----------------
// q -> qws [h][s][d]; k,v -> present rows PASTN..PASTN+31
__global__ __launch_bounds__(256) void qkv_kernel(
    const float* __restrict__ x, const float* __restrict__ w,
    const float* __restrict__ b, float* __restrict__ qws,
    float* __restrict__ present)
{
    int idx = blockIdx.x * 256 + threadIdx.x;      // 32*3072 = 98304
    int s = idx / 3072;
    int col = idx - s * 3072;
    const float* xr = x + s * NE;
    float a0 = 0.f, a1 = 0.f, a2 = 0.f, a3 = 0.f;  // 4 chains for ILP
    for (int k = 0; k < NE; k += 4) {
        a0 = fmaf(xr[k + 0], w[(k + 0) * 3072 + col], a0);
        a1 = fmaf(xr[k + 1], w[(k + 1) * 3072 + col], a1);
        a2 = fmaf(xr[k + 2], w[(k + 2) * 3072 + col], a2);
        a3 = fmaf(xr[k + 3], w[(k + 3) * 3072 + col], a3);
    }
    float acc = b[col] + ((a0 + a1) + (a2 + a3));
    int g = col >> 10;          // 0=q, 1=k, 2=v
    int e = col & 1023;
    int h = e >> 6, d = e & 63;
    if (g == 0)
        qws[(h * SEQL + s) * HD + d] = acc;
    else
        present[(((g - 1) * HEADS + h) * TOTN + PASTN + s) * HD + d] = acc;
}

// ------- kernel 2: fused cache-copy + flash-decode partials -------
// block = (head h, chunk c). Chunks 0..63: 512 past keys (copied to
// present while computing). Chunk 64: the 32 new keys (causal-masked).
__global__ __launch_bounds__(256) void attn_partial(
    const float* __restrict__ past, const float* __restrict__ qws,
    float* __restrict__ present, float* __restrict__ opart,
    float* __restrict__ mws, float* __restrict__ lws)
{
    int h = blockIdx.x / NCHUNK;
    int c = blockIdx.x - h * NCHUNK;
    __shared__ __align__(16) float Qs[SEQL][HD];   // 8 KB
    __shared__ __align__(16) float Ks[KT][HD];     // 8 KB, 16B-granule XOR swizzle
    __shared__ __align__(16) float Vs[KT][HD];     // 8 KB, same swizzle
    __shared__ __align__(16) float Ss[SEQL][SLDP]; // 4.6 KB
    __shared__ float mrow[SEQL], lrow[SEQL], arow[SEQL];
    int tid = threadIdx.x;

    // stage Q (plain layout; reads are wave-uniform broadcasts)
    for (int i = tid; i < SEQL * 16; i += 256) {
        int q = i >> 4, s4 = i & 15;
        *(float4*)&Qs[q][s4 * 4] = *(const float4*)&qws[(h * SEQL + q) * HD + s4 * 4];
    }
    if (tid < SEQL) { mrow[tid] = -3e38f; lrow[tid] = 0.f; }

    float acc[8];   // [j][0]=d, [j][1]=d+32 for 4 query rows
#pragma unroll
    for (int j = 0; j < 8; ++j) acc[j] = 0.f;

    int lk = tid & 31;          // scores: key index; PV: d lane
    int q0 = (tid >> 5) * 4;    // 4 query rows per thread
    int nkeys = (c < NPC) ? CHUNK : SEQL;
    int kstart = c * CHUNK;     // c==64 -> 32768 (the new keys)
    __syncthreads();

    for (int t0 = 0; t0 < nkeys; t0 += KT) {
        // ---- stage K/V tile (swizzled); past chunks also copy to present ----
        if (c < NPC) {
#pragma unroll
            for (int rep = 0; rep < 2; ++rep) {
                int i = tid + rep * 256;            // KT*16 = 512 float4s
                int row = i >> 4, s4 = i & 15;
                int grow = kstart + t0 + row;
                float4 kk = *(const float4*)&past[(h * PASTN + grow) * HD + s4 * 4];
                float4 vv = *(const float4*)&past[((HEADS + h) * PASTN + grow) * HD + s4 * 4];
                *(float4*)&present[(h * TOTN + grow) * HD + s4 * 4] = kk;
                *(float4*)&present[((HEADS + h) * TOTN + grow) * HD + s4 * 4] = vv;
                int sl = (s4 ^ (row & 7)) * 4;      // XOR swizzle in 16B slots
                *(float4*)&Ks[row][sl] = kk;
                *(float4*)&Vs[row][sl] = vv;
            }
        } else {
#pragma unroll
            for (int rep = 0; rep < 2; ++rep) {
                int i = tid + rep * 256;
                int row = i >> 4, s4 = i & 15;
                int grow = PASTN + t0 + row;
                float4 kk = *(const float4*)&present[(h * TOTN + grow) * HD + s4 * 4];
                float4 vv = *(const float4*)&present[((HEADS + h) * TOTN + grow) * HD + s4 * 4];
                int sl = (s4 ^ (row & 7)) * 4;
                *(float4*)&Ks[row][sl] = kk;
                *(float4*)&Vs[row][sl] = vv;
            }
        }
        __syncthreads();

        // ---- scores: 4 q-rows x 1 key per thread, float4 d-steps ----
        {
            float s0 = 0.f, s1 = 0.f, s2 = 0.f, s3 = 0.f;
            int xr = lk & 7;
#pragma unroll
            for (int d4 = 0; d4 < 16; ++d4) {
                float4 kk = *(const float4*)&Ks[lk][(d4 ^ xr) * 4];
                float4 r0 = *(const float4*)&Qs[q0 + 0][d4 * 4];
                float4 r1 = *(const float4*)&Qs[q0 + 1][d4 * 4];
                float4 r2 = *(const float4*)&Qs[q0 + 2][d4 * 4];
                float4 r3 = *(const float4*)&Qs[q0 + 3][d4 * 4];
                s0 = fmaf(r0.x, kk.x, s0); s0 = fmaf(r0.y, kk.y, s0);
                s0 = fmaf(r0.z, kk.z, s0); s0 = fmaf(r0.w, kk.w, s0);
                s1 = fmaf(r1.x, kk.x, s1); s1 = fmaf(r1.y, kk.y, s1);
                s1 = fmaf(r1.z, kk.z, s1); s1 = fmaf(r1.w, kk.w, s1);
                s2 = fmaf(r2.x, kk.x, s2); s2 = fmaf(r2.y, kk.y, s2);
                s2 = fmaf(r2.z, kk.z, s2); s2 = fmaf(r2.w, kk.w, s2);
                s3 = fmaf(r3.x, kk.x, s3); s3 = fmaf(r3.y, kk.y, s3);
                s3 = fmaf(r3.z, kk.z, s3); s3 = fmaf(r3.w, kk.w, s3);
            }
            s0 *= 0.125f; s1 *= 0.125f; s2 *= 0.125f; s3 *= 0.125f;
            if (c == NPC) {                 // causal mask on new keys
                if (lk > q0 + 0) s0 = NEGV;
                if (lk > q0 + 1) s1 = NEGV;
                if (lk > q0 + 2) s2 = NEGV;
                if (lk > q0 + 3) s3 = NEGV;
            }
            Ss[q0 + 0][lk] = s0;
            Ss[q0 + 1][lk] = s1;
            Ss[q0 + 2][lk] = s2;
            Ss[q0 + 3][lk] = s3;
        }
        __syncthreads();

        // ---- online softmax: 8 lanes per q-row, shuffle reduce ----
        {
            int q = tid >> 3, sub = tid & 7;
            float4 sv = *(const float4*)&Ss[q][sub * 4];
            float mt = fmaxf(fmaxf(sv.x, sv.y), fmaxf(sv.z, sv.w));
            mt = fmaxf(mt, __shfl_xor(mt, 1));
            mt = fmaxf(mt, __shfl_xor(mt, 2));
            mt = fmaxf(mt, __shfl_xor(mt, 4));
            float mold = mrow[q];
            float mnew = fmaxf(mold, mt);
            float4 p;
            p.x = __expf(sv.x - mnew);
            p.y = __expf(sv.y - mnew);
            p.z = __expf(sv.z - mnew);
            p.w = __expf(sv.w - mnew);
            *(float4*)&Ss[q][sub * 4] = p;
            float ls = (p.x + p.y) + (p.z + p.w);
            ls += __shfl_xor(ls, 1);
            ls += __shfl_xor(ls, 2);
            ls += __shfl_xor(ls, 4);
            if (sub == 0) {
                float alpha = __expf(mold - mnew);
                lrow[q] = lrow[q] * alpha + ls;
                mrow[q] = mnew;
                arow[q] = alpha;
            }
        }
        __syncthreads();

        // ---- PV: 4 q-rows x (d, d+32) per thread ----
        {
            int dq = lk >> 2, dr = lk & 3;
#pragma unroll
            for (int j = 0; j < 4; ++j) {
                float aj = arow[q0 + j];
                acc[2 * j] *= aj;
                acc[2 * j + 1] *= aj;
            }
#pragma unroll
            for (int t4 = 0; t4 < KT; t4 += 4) {
                float va[4], vb[4];
#pragma unroll
                for (int u = 0; u < 4; ++u) {
                    int t = t4 + u;
                    int sl = ((dq ^ (t & 7)) * 4) + dr;   // d slot
                    va[u] = Vs[t][sl];
                    vb[u] = Vs[t][sl + 32];               // d+32: slot idx +8
                }
#pragma unroll
                for (int j = 0; j < 4; ++j) {
                    float4 pv = *(const float4*)&Ss[q0 + j][t4];
                    float u1 = acc[2 * j], u2 = acc[2 * j + 1];
                    u1 = fmaf(pv.x, va[0], u1); u1 = fmaf(pv.y, va[1], u1);
                    u1 = fmaf(pv.z, va[2], u1); u1 = fmaf(pv.w, va[3], u1);
                    u2 = fmaf(pv.x, vb[0], u2); u2 = fmaf(pv.y, vb[1], u2);
                    u2 = fmaf(pv.z, vb[2], u2); u2 = fmaf(pv.w, vb[3], u2);
                    acc[2 * j] = u1; acc[2 * j + 1] = u2;
                }
            }
        }
        __syncthreads();   // protect Ks/Vs/Ss for next tile
    }

    // ---- write partials ----
    if (tid < SEQL) {
        mws[(h * NCHUNK + c) * SEQL + tid] = mrow[tid];
        lws[(h * NCHUNK + c) * SEQL + tid] = lrow[tid];
    }
#pragma unroll
    for (int j = 0; j < 4; ++j) {
        int q = q0 + j;
        opart[((h * NCHUNK + c) * SEQL + q) * HD + lk] = acc[2 * j];
        opart[((h * NCHUNK + c) * SEQL + q) * HD + lk + 32] = acc[2 * j + 1];
    }
}

// -------- kernel 3: combine chunk partials, merge heads --------
__global__ __launch_bounds__(64) void attn_reduce(
    const float* __restrict__ opart, const float* __restrict__ mws,
    const float* __restrict__ lws, float* __restrict__ aws)
{
    int h = blockIdx.x >> 5;
    int q = blockIdx.x & 31;
    int d = threadIdx.x;
    float M = -3e38f;
    for (int c = 0; c < NCHUNK; ++c)
        M = fmaxf(M, mws[(h * NCHUNK + c) * SEQL + q]);
    float L = 0.f, o = 0.f;
    for (int c = 0; c < NCHUNK; ++c) {
        float wgt = __expf(mws[(h * NCHUNK + c) * SEQL + q] - M);
        L = fmaf(lws[(h * NCHUNK + c) * SEQL + q], wgt, L);
        o = fmaf(opart[((h * NCHUNK + c) * SEQL + q) * HD + d], wgt, o);
    }
    aws[q * NE + h * HD + d] = o / L;   // merged heads: [s][e]
}

// -------- kernel 4: out = a @ w_proj + b_proj --------
__global__ __launch_bounds__(256) void proj_kernel(
    const float* __restrict__ aws, const float* __restrict__ w,
    const float* __restrict__ b, float* __restrict__ out)
{
    int idx = blockIdx.x * 256 + threadIdx.x;   // 32*1024
    int s = idx >> 10, e = idx & 1023;
    const float* ar = aws + s * NE;
    float a0 = 0.f, a1 = 0.f, a2 = 0.f, a3 = 0.f;
    for (int k = 0; k < NE; k += 4) {
        a0 = fmaf(ar[k + 0], w[(k + 0) * NE + e], a0);
        a1 = fmaf(ar[k + 1], w[(k + 1) * NE + e], a1);
        a2 = fmaf(ar[k + 2], w[(k + 2) * NE + e], a2);
        a3 = fmaf(ar[k + 3], w[(k + 3) * NE + e], a3);
    }
    out[idx] = b[e] + ((a0 + a1) + (a2 + a3));
}

extern "C" void kernel_launch(void* const* d_in, const int* in_sizes, int n_in,
                              void* d_out, int out_size, void* d_ws, size_t ws_size,
                              hipStream_t stream) {
    const float* x      = (const float*)d_in[0];
    const float* past   = (const float*)d_in[1];   // [2,16,32768,64]
    const float* w_attn = (const float*)d_in[2];   // [1024,3072]
    const float* b_attn = (const float*)d_in[3];
    const float* w_proj = (const float*)d_in[4];   // [1024,1024]
    const float* b_proj = (const float*)d_in[5];

    float* out     = (float*)d_out;                 // [32,1024]
    float* present = out + SEQL * NE;               // [2,16,32800,64]

    // workspace layout (floats)
    float* wsf   = (float*)d_ws;
    float* qws   = wsf;                     // 16*32*64      = 32768
    float* aws   = wsf + 32768;             // 32*1024       = 32768
    float* mws   = wsf + 65536;             // 16*65*32      = 33280
    float* lws   = mws + 33280;             // 33280
    float* opart = lws + 33280;             // 16*65*32*64   = 2129920

    qkv_kernel<<<(SEQL * 3072) / 256, 256, 0, stream>>>(x, w_attn, b_attn, qws, present);
    attn_partial<<<HEADS * NCHUNK, 256, 0, stream>>>(past, qws, present, opart, mws, lws);
    attn_reduce<<<HEADS * SEQL, 64, 0, stream>>>(opart, mws, lws, aws);
    proj_kernel<<<(SEQL * NE) / 256, 256, 0, stream>>>(aws, w_proj, b_proj, out);
}

// Round 2
// 579.707 us; speedup vs baseline: 1.5278x; 1.0738x over previous
//
#include <hip/hip_runtime.h>

#define HEADS 16
#define SEQL 32
#define HD 64
#define PASTN 32768
#define TOTN 32800
#define NE 1024
#define CHUNK 1024     // keys per past chunk
#define NPC 32         // number of past chunks
#define NCHUNK 33      // 32 past chunks + 1 new-key chunk
#define KT 64          // keys per LDS tile
#define LDP 68         // LDS leading dim: 68%32=4 -> rows shift 4 banks/row
#define NEGV -10000.0f

// ---------------- kernel 1: qkv = x @ w_attn + b_attn ----------------
__global__ __launch_bounds__(256) void qkv_kernel(
    const float* __restrict__ x, const float* __restrict__ w,
    const float* __restrict__ b, float* __restrict__ qws,
    float* __restrict__ present)
{
    int idx = blockIdx.x * 256 + threadIdx.x;      // 32*3072 = 98304
    int s = idx / 3072;
    int col = idx - s * 3072;
    const float4* x4 = (const float4*)(x + s * NE);
    float a0 = 0.f, a1 = 0.f, a2 = 0.f, a3 = 0.f;
#pragma unroll 8
    for (int k4 = 0; k4 < NE / 4; ++k4) {
        float4 xv = x4[k4];
        const float* wp = w + (k4 * 4) * 3072 + col;
        a0 = fmaf(xv.x, wp[0],        a0);
        a1 = fmaf(xv.y, wp[3072],     a1);
        a2 = fmaf(xv.z, wp[2 * 3072], a2);
        a3 = fmaf(xv.w, wp[3 * 3072], a3);
    }
    float acc = b[col] + ((a0 + a1) + (a2 + a3));
    int g = col >> 10;          // 0=q, 1=k, 2=v
    int e = col & 1023;
    int h = e >> 6, d = e & 63;
    if (g == 0)
        qws[(h * SEQL + s) * HD + d] = acc;
    else
        present[(((g - 1) * HEADS + h) * TOTN + PASTN + s) * HD + d] = acc;
}

// ------- kernel 2: fused cache-copy + flash-decode partials -------
// block = (head h, chunk c). Chunks 0..31: 1024 past keys (copied to
// present while computing). Chunk 32: the 32 new keys (causal-masked).
// 256 threads; scores/PV run on threads 0..127 with 4x4 register tiles.
__global__ __launch_bounds__(256) void attn_partial(
    const float* __restrict__ past, const float* __restrict__ qws,
    float* __restrict__ present, float* __restrict__ opart,
    float* __restrict__ mws, float* __restrict__ lws)
{
    int h = blockIdx.x / NCHUNK;
    int c = blockIdx.x - h * NCHUNK;
    __shared__ __align__(16) float Qs[SEQL][LDP];   // 8.5 KB
    __shared__ __align__(16) float Ks[KT][LDP];     // 17 KB
    __shared__ __align__(16) float Vs[KT][LDP];     // 17 KB
    __shared__ __align__(16) float Ss[SEQL][LDP];   // 8.5 KB
    __shared__ float mrow[SEQL], lrow[SEQL], arow[SEQL];
    int tid = threadIdx.x;

    // stage Q
    for (int i = tid; i < SEQL * 16; i += 256) {
        int q = i >> 4, s4 = i & 15;
        *(float4*)&Qs[q][s4 * 4] = *(const float4*)&qws[(h * SEQL + q) * HD + s4 * 4];
    }
    if (tid < SEQL) { mrow[tid] = -3e38f; lrow[tid] = 0.f; }

    float4 acc4[4];
#pragma unroll
    for (int j = 0; j < 4; ++j) acc4[j] = make_float4(0.f, 0.f, 0.f, 0.f);

    int qg = tid >> 4;          // 0..7 (for tid<128)
    int lg = tid & 15;          // scores: k-group base; PV: d-group
    int nkeys = (c < NPC) ? CHUNK : KT;   // NPC chunk: single KT tile
    int kstart = c * CHUNK;
    __syncthreads();

    for (int t0 = 0; t0 < nkeys; t0 += KT) {
        // ---- stage K/V tile; past chunks also copy to present ----
        if (c < NPC) {
#pragma unroll
            for (int rep = 0; rep < 4; ++rep) {
                int i = tid + rep * 256;            // KT*16 = 1024 float4s
                int row = i >> 4, s4 = i & 15;
                int grow = kstart + t0 + row;
                float4 kk = *(const float4*)&past[(h * PASTN + grow) * HD + s4 * 4];
                float4 vv = *(const float4*)&past[((HEADS + h) * PASTN + grow) * HD + s4 * 4];
                *(float4*)&present[(h * TOTN + grow) * HD + s4 * 4] = kk;
                *(float4*)&present[((HEADS + h) * TOTN + grow) * HD + s4 * 4] = vv;
                *(float4*)&Ks[row][s4 * 4] = kk;
                *(float4*)&Vs[row][s4 * 4] = vv;
            }
        } else {
            // zero V rows 32..63 (read by PV with p==0; avoid NaN garbage)
            float* vz = &Vs[SEQL][0];
            for (int i = tid; i < (KT - SEQL) * LDP; i += 256) vz[i] = 0.f;
#pragma unroll
            for (int rep = 0; rep < 2; ++rep) {
                int i = tid + rep * 256;            // rows 0..31
                int row = i >> 4, s4 = i & 15;
                int grow = PASTN + row;
                float4 kk = *(const float4*)&present[(h * TOTN + grow) * HD + s4 * 4];
                float4 vv = *(const float4*)&present[((HEADS + h) * TOTN + grow) * HD + s4 * 4];
                *(float4*)&Ks[row][s4 * 4] = kk;
                *(float4*)&Vs[row][s4 * 4] = vv;
            }
        }
        __syncthreads();

        // ---- scores: threads 0..127, 4q x 4k register tile (k strided 16) ----
        if (tid < 128) {
            float s[4][4];
#pragma unroll
            for (int j = 0; j < 4; ++j)
#pragma unroll
                for (int u = 0; u < 4; ++u) s[j][u] = 0.f;
#pragma unroll
            for (int d4 = 0; d4 < 16; ++d4) {
                float4 qv[4], kv[4];
#pragma unroll
                for (int j = 0; j < 4; ++j)
                    qv[j] = *(const float4*)&Qs[qg * 4 + j][d4 * 4];
#pragma unroll
                for (int u = 0; u < 4; ++u)
                    kv[u] = *(const float4*)&Ks[lg + u * 16][d4 * 4];
#pragma unroll
                for (int j = 0; j < 4; ++j)
#pragma unroll
                    for (int u = 0; u < 4; ++u) {
                        s[j][u] = fmaf(qv[j].x, kv[u].x, s[j][u]);
                        s[j][u] = fmaf(qv[j].y, kv[u].y, s[j][u]);
                        s[j][u] = fmaf(qv[j].z, kv[u].z, s[j][u]);
                        s[j][u] = fmaf(qv[j].w, kv[u].w, s[j][u]);
                    }
            }
#pragma unroll
            for (int j = 0; j < 4; ++j) {
                int q = qg * 4 + j;
#pragma unroll
                for (int u = 0; u < 4; ++u) {
                    float sv = s[j][u] * 0.125f;    // 1/sqrt(64)
                    if (c == NPC && (lg + u * 16) > q) sv = NEGV;
                    Ss[q][lg + u * 16] = sv;
                }
            }
        }
        __syncthreads();

        // ---- online softmax: 8 lanes per q-row, strided cols ----
        {
            int q = tid >> 3, sub = tid & 7;
            float v[8];
#pragma unroll
            for (int i = 0; i < 8; ++i) v[i] = Ss[q][sub + 8 * i];
            float mt = fmaxf(fmaxf(fmaxf(v[0], v[1]), fmaxf(v[2], v[3])),
                             fmaxf(fmaxf(v[4], v[5]), fmaxf(v[6], v[7])));
            mt = fmaxf(mt, __shfl_xor(mt, 1));
            mt = fmaxf(mt, __shfl_xor(mt, 2));
            mt = fmaxf(mt, __shfl_xor(mt, 4));
            float mold = mrow[q];
            float mnew = fmaxf(mold, mt);
            float ls = 0.f;
#pragma unroll
            for (int i = 0; i < 8; ++i) {
                float p = __expf(v[i] - mnew);
                Ss[q][sub + 8 * i] = p;
                ls += p;
            }
            ls += __shfl_xor(ls, 1);
            ls += __shfl_xor(ls, 2);
            ls += __shfl_xor(ls, 4);
            if (sub == 0) {
                float alpha = __expf(mold - mnew);
                lrow[q] = lrow[q] * alpha + ls;
                mrow[q] = mnew;
                arow[q] = alpha;
            }
        }
        __syncthreads();

        // ---- PV: threads 0..127, 4q x 4d register tile ----
        if (tid < 128) {
#pragma unroll
            for (int j = 0; j < 4; ++j) {
                float aj = arow[qg * 4 + j];
                acc4[j].x *= aj; acc4[j].y *= aj; acc4[j].z *= aj; acc4[j].w *= aj;
            }
#pragma unroll
            for (int t4 = 0; t4 < 16; ++t4) {
                float4 vv[4];
#pragma unroll
                for (int u = 0; u < 4; ++u)
                    vv[u] = *(const float4*)&Vs[t4 * 4 + u][lg * 4];
#pragma unroll
                for (int j = 0; j < 4; ++j) {
                    float4 p = *(const float4*)&Ss[qg * 4 + j][t4 * 4];
                    acc4[j].x = fmaf(p.x, vv[0].x, acc4[j].x);
                    acc4[j].x = fmaf(p.y, vv[1].x, acc4[j].x);
                    acc4[j].x = fmaf(p.z, vv[2].x, acc4[j].x);
                    acc4[j].x = fmaf(p.w, vv[3].x, acc4[j].x);
                    acc4[j].y = fmaf(p.x, vv[0].y, acc4[j].y);
                    acc4[j].y = fmaf(p.y, vv[1].y, acc4[j].y);
                    acc4[j].y = fmaf(p.z, vv[2].y, acc4[j].y);
                    acc4[j].y = fmaf(p.w, vv[3].y, acc4[j].y);
                    acc4[j].z = fmaf(p.x, vv[0].z, acc4[j].z);
                    acc4[j].z = fmaf(p.y, vv[1].z, acc4[j].z);
                    acc4[j].z = fmaf(p.z, vv[2].z, acc4[j].z);
                    acc4[j].z = fmaf(p.w, vv[3].z, acc4[j].z);
                    acc4[j].w = fmaf(p.x, vv[0].w, acc4[j].w);
                    acc4[j].w = fmaf(p.y, vv[1].w, acc4[j].w);
                    acc4[j].w = fmaf(p.z, vv[2].w, acc4[j].w);
                    acc4[j].w = fmaf(p.w, vv[3].w, acc4[j].w);
                }
            }
        }
        __syncthreads();   // protect Ks/Vs/Ss for next tile
    }

    // ---- write partials ----
    if (tid < SEQL) {
        mws[(h * NCHUNK + c) * SEQL + tid] = mrow[tid];
        lws[(h * NCHUNK + c) * SEQL + tid] = lrow[tid];
    }
    if (tid < 128) {
#pragma unroll
        for (int j = 0; j < 4; ++j) {
            int q = qg * 4 + j;
            *(float4*)&opart[((h * NCHUNK + c) * SEQL + q) * HD + lg * 4] = acc4[j];
        }
    }
}

// -------- kernel 3: combine chunk partials, merge heads --------
__global__ __launch_bounds__(64) void attn_reduce(
    const float* __restrict__ opart, const float* __restrict__ mws,
    const float* __restrict__ lws, float* __restrict__ aws)
{
    int h = blockIdx.x >> 5;
    int q = blockIdx.x & 31;
    int d = threadIdx.x;
    float M = -3e38f;
    for (int c = 0; c < NCHUNK; ++c)
        M = fmaxf(M, mws[(h * NCHUNK + c) * SEQL + q]);
    float L = 0.f, o = 0.f;
    for (int c = 0; c < NCHUNK; ++c) {
        float wgt = __expf(mws[(h * NCHUNK + c) * SEQL + q] - M);
        L = fmaf(lws[(h * NCHUNK + c) * SEQL + q], wgt, L);
        o = fmaf(opart[((h * NCHUNK + c) * SEQL + q) * HD + d], wgt, o);
    }
    aws[q * NE + h * HD + d] = o / L;   // merged heads: [s][e]
}

// -------- kernel 4: out = a @ w_proj + b_proj --------
__global__ __launch_bounds__(256) void proj_kernel(
    const float* __restrict__ aws, const float* __restrict__ w,
    const float* __restrict__ b, float* __restrict__ out)
{
    int idx = blockIdx.x * 256 + threadIdx.x;   // 32*1024
    int s = idx >> 10, e = idx & 1023;
    const float4* a4 = (const float4*)(aws + s * NE);
    float a0 = 0.f, a1 = 0.f, a2 = 0.f, a3 = 0.f;
#pragma unroll 8
    for (int k4 = 0; k4 < NE / 4; ++k4) {
        float4 xv = a4[k4];
        const float* wp = w + (k4 * 4) * NE + e;
        a0 = fmaf(xv.x, wp[0],      a0);
        a1 = fmaf(xv.y, wp[NE],     a1);
        a2 = fmaf(xv.z, wp[2 * NE], a2);
        a3 = fmaf(xv.w, wp[3 * NE], a3);
    }
    out[idx] = b[e] + ((a0 + a1) + (a2 + a3));
}

extern "C" void kernel_launch(void* const* d_in, const int* in_sizes, int n_in,
                              void* d_out, int out_size, void* d_ws, size_t ws_size,
                              hipStream_t stream) {
    const float* x      = (const float*)d_in[0];
    const float* past   = (const float*)d_in[1];   // [2,16,32768,64]
    const float* w_attn = (const float*)d_in[2];   // [1024,3072]
    const float* b_attn = (const float*)d_in[3];
    const float* w_proj = (const float*)d_in[4];   // [1024,1024]
    const float* b_proj = (const float*)d_in[5];

    float* out     = (float*)d_out;                 // [32,1024]
    float* present = out + SEQL * NE;               // [2,16,32800,64]

    // workspace layout (floats)
    float* wsf   = (float*)d_ws;
    float* qws   = wsf;                     // 16*32*64      = 32768
    float* aws   = wsf + 32768;             // 32*1024       = 32768
    float* mws   = wsf + 65536;             // 16*33*32      = 16896
    float* lws   = mws + 16896;             // 16896
    float* opart = lws + 16896;             // 16*33*32*64   = 1081344

    qkv_kernel<<<(SEQL * 3072) / 256, 256, 0, stream>>>(x, w_attn, b_attn, qws, present);
    attn_partial<<<HEADS * NCHUNK, 256, 0, stream>>>(past, qws, present, opart, mws, lws);
    attn_reduce<<<HEADS * SEQL, 64, 0, stream>>>(opart, mws, lws, aws);
    proj_kernel<<<(SEQL * NE) / 256, 256, 0, stream>>>(aws, w_proj, b_proj, out);
}